// Round 2
// baseline (1118.390 us; speedup 1.0000x reference)
//
#include <hip/hip_runtime.h>
#include <hip/hip_bf16.h>

#define Hh 128
#define Ww 160
#define Cc 32
#define Dd 48
#define Bb 2
#define Vv 3
#define HW (Hh*Ww)
#define CP2 20   // padded stride for 16-channel half-tile (16 + 4 pad floats)

// ---------------- K0: proj = src_proj @ inv(ref_proj), extract rot/trans ----
__global__ void k_proj(const float* __restrict__ pm, float* __restrict__ P) {
    int t = threadIdx.x;
    if (t >= Bb * (Vv - 1)) return;
    int b = t >> 1;
    int v = (t & 1) + 1;
    const float* ref = pm + (b * Vv + 0) * 16;
    const float* src = pm + (b * Vv + v) * 16;
    float A[4][8];
    for (int i = 0; i < 4; ++i)
        for (int j = 0; j < 4; ++j) {
            A[i][j] = ref[i * 4 + j];
            A[i][4 + j] = (i == j) ? 1.0f : 0.0f;
        }
    for (int col = 0; col < 4; ++col) {
        int piv = col;
        for (int r = col + 1; r < 4; ++r)
            if (fabsf(A[r][col]) > fabsf(A[piv][col])) piv = r;
        if (piv != col)
            for (int j = 0; j < 8; ++j) { float tmp = A[col][j]; A[col][j] = A[piv][j]; A[piv][j] = tmp; }
        float inv = 1.0f / A[col][col];
        for (int j = 0; j < 8; ++j) A[col][j] *= inv;
        for (int r = 0; r < 4; ++r) {
            if (r == col) continue;
            float f = A[r][col];
            for (int j = 0; j < 8; ++j) A[r][j] -= f * A[col][j];
        }
    }
    float Pm[3][4];
    for (int i = 0; i < 3; ++i)
        for (int j = 0; j < 4; ++j) {
            float s = 0.f;
            for (int k = 0; k < 4; ++k) s += src[i * 4 + k] * A[k][4 + j];
            Pm[i][j] = s;
        }
    float* o = P + t * 12;
    o[0] = Pm[0][0]; o[1] = Pm[0][1]; o[2] = Pm[0][2];
    o[3] = Pm[1][0]; o[4] = Pm[1][1]; o[5] = Pm[1][2];
    o[6] = Pm[2][0]; o[7] = Pm[2][1]; o[8] = Pm[2][2];
    o[9] = Pm[0][3]; o[10] = Pm[1][3]; o[11] = Pm[2][3];
}

// ---------------- K1: transpose (v,b,c,h,w) -> (v,b,h,w,c) ------------------
__global__ void k_transpose(const float* __restrict__ f, float* __restrict__ featT) {
    __shared__ float t[Cc][Ww + 1];
    int slice = blockIdx.x;          // vb*H + y
    int vb = slice / Hh, y = slice % Hh;
    const float* src = f + (size_t)vb * Cc * HW + (size_t)y * Ww;
    float* dst = featT + ((size_t)vb * Hh + y) * Ww * Cc;
    for (int i = threadIdx.x; i < Cc * Ww; i += 256) {
        int c = i / Ww, x = i - c * Ww;
        t[c][x] = src[(size_t)c * HW + x];
    }
    __syncthreads();
    for (int i = threadIdx.x; i < Cc * Ww; i += 256) {
        int x = i >> 5, c = i & 31;
        dst[i] = t[c][x];
    }
}

// ---------------- K2: variance tile + channel-contracted 3x3 conv -> S ------
// Two 16-channel halves through a 26 KB LDS tile -> 6 blocks/CU (was 3).
__global__ __launch_bounds__(256, 6)
void k_main(const float* __restrict__ featT, const float* __restrict__ P,
            const float* __restrict__ dvals, const float* __restrict__ wt,
            float* __restrict__ S) {
    __shared__ float vsh[324 * CP2];
    __shared__ float rt[24];
    const int tid = threadIdx.x;
    const int b = blockIdx.z, d = blockIdx.y;
    const int tileY = blockIdx.x / 10, tileX = blockIdx.x - (blockIdx.x / 10) * 10;

    if (tid < 24) rt[tid] = P[b * 24 + tid];
    const float depth = dvals[b * Dd + d];
    const int ty = tid >> 4, tx = tid & 15;
    float acc0 = 0.f, acc1 = 0.f, acc2 = 0.f;
    __syncthreads();

    for (int half = 0; half < 2; ++half) {
        const int coff = half * 16;   // channel offset (floats) into featT pixel

        // ---- phase 1: fill 18x18 halo variance tile for 16 channels ----
        for (int p = tid; p < 324; p += 256) {
            int pyt = p / 18, pxt = p - pyt * 18;
            int gy = tileY * 16 + pyt - 1, gx = tileX * 16 + pxt - 1;
            float* dst = &vsh[p * CP2];
            if ((unsigned)gy >= (unsigned)Hh || (unsigned)gx >= (unsigned)Ww) {
                float4 z4 = make_float4(0.f, 0.f, 0.f, 0.f);
#pragma unroll
                for (int c4 = 0; c4 < 4; ++c4) *(float4*)&dst[c4 * 4] = z4;
                continue;
            }
            const float* q[2][4];
            float wgt[2][4];
#pragma unroll
            for (int vi = 0; vi < 2; ++vi) {
                const float* M = &rt[vi * 12];
                float fgx = (float)gx, fgy = (float)gy;
                float rx = M[0] * fgx + M[1] * fgy + M[2];
                float ry = M[3] * fgx + M[4] * fgy + M[5];
                float rz = M[6] * fgx + M[7] * fgy + M[8];
                float X = rx * depth + M[9];
                float Y = ry * depth + M[10];
                float Z = rz * depth + M[11];
                float z = (fabsf(Z) < 1e-6f) ? 1e-6f : Z;
                float u = X / z, vv = Y / z;
                float x0f = floorf(u), y0f = floorf(vv);
                float fx = u - x0f, fy = vv - y0f;
                int x0 = (int)x0f, y0 = (int)y0f;
                int x1 = x0 + 1, y1 = y0 + 1;
                bool vx0 = (x0 >= 0) && (x0 <= Ww - 1);
                bool vx1 = (x1 >= 0) && (x1 <= Ww - 1);
                bool vy0 = (y0 >= 0) && (y0 <= Hh - 1);
                bool vy1 = (y1 >= 0) && (y1 <= Hh - 1);
                int xc0 = min(max(x0, 0), Ww - 1), xc1 = min(max(x1, 0), Ww - 1);
                int yc0 = min(max(y0, 0), Hh - 1), yc1 = min(max(y1, 0), Hh - 1);
                const float* base = featT + (size_t)((vi + 1) * Bb + b) * Hh * Ww * Cc + coff;
                q[vi][0] = base + ((size_t)yc0 * Ww + xc0) * Cc;
                q[vi][1] = base + ((size_t)yc0 * Ww + xc1) * Cc;
                q[vi][2] = base + ((size_t)yc1 * Ww + xc0) * Cc;
                q[vi][3] = base + ((size_t)yc1 * Ww + xc1) * Cc;
                wgt[vi][0] = (vx0 && vy0) ? (1.f - fx) * (1.f - fy) : 0.f;
                wgt[vi][1] = (vx1 && vy0) ? fx * (1.f - fy) : 0.f;
                wgt[vi][2] = (vx0 && vy1) ? (1.f - fx) * fy : 0.f;
                wgt[vi][3] = (vx1 && vy1) ? fx * fy : 0.f;
            }
            const float* pref = featT + ((size_t)(0 * Bb + b) * Hh + gy) * Ww * Cc + (size_t)gx * Cc + coff;
#pragma unroll
            for (int c4 = 0; c4 < 4; ++c4) {
                float4 r = *(const float4*)(pref + c4 * 4);
                float4 a00 = *(const float4*)(q[0][0] + c4 * 4);
                float4 a01 = *(const float4*)(q[0][1] + c4 * 4);
                float4 a10 = *(const float4*)(q[0][2] + c4 * 4);
                float4 a11 = *(const float4*)(q[0][3] + c4 * 4);
                float4 b00 = *(const float4*)(q[1][0] + c4 * 4);
                float4 b01 = *(const float4*)(q[1][1] + c4 * 4);
                float4 b10 = *(const float4*)(q[1][2] + c4 * 4);
                float4 b11 = *(const float4*)(q[1][3] + c4 * 4);
                float4 s1, s2, sum, var;
                s1.x = wgt[0][0] * a00.x + wgt[0][1] * a01.x + wgt[0][2] * a10.x + wgt[0][3] * a11.x;
                s1.y = wgt[0][0] * a00.y + wgt[0][1] * a01.y + wgt[0][2] * a10.y + wgt[0][3] * a11.y;
                s1.z = wgt[0][0] * a00.z + wgt[0][1] * a01.z + wgt[0][2] * a10.z + wgt[0][3] * a11.z;
                s1.w = wgt[0][0] * a00.w + wgt[0][1] * a01.w + wgt[0][2] * a10.w + wgt[0][3] * a11.w;
                s2.x = wgt[1][0] * b00.x + wgt[1][1] * b01.x + wgt[1][2] * b10.x + wgt[1][3] * b11.x;
                s2.y = wgt[1][0] * b00.y + wgt[1][1] * b01.y + wgt[1][2] * b10.y + wgt[1][3] * b11.y;
                s2.z = wgt[1][0] * b00.z + wgt[1][1] * b01.z + wgt[1][2] * b10.z + wgt[1][3] * b11.z;
                s2.w = wgt[1][0] * b00.w + wgt[1][1] * b01.w + wgt[1][2] * b10.w + wgt[1][3] * b11.w;
                const float i3 = 1.0f / 3.0f, i9 = 1.0f / 9.0f;
                sum.x = r.x + s1.x + s2.x; sum.y = r.y + s1.y + s2.y;
                sum.z = r.z + s1.z + s2.z; sum.w = r.w + s1.w + s2.w;
                var.x = (r.x * r.x + s1.x * s1.x + s2.x * s2.x) * i3 - sum.x * sum.x * i9;
                var.y = (r.y * r.y + s1.y * s1.y + s2.y * s2.y) * i3 - sum.y * sum.y * i9;
                var.z = (r.z * r.z + s1.z * s1.z + s2.z * s2.z) * i3 - sum.z * sum.z * i9;
                var.w = (r.w * r.w + s1.w * s1.w + s2.w * s2.w) * i3 - sum.w * sum.w * i9;
                *(float4*)&dst[c4 * 4] = var;
            }
        }
        __syncthreads();

        // ---- phase 2: 3x3 conv over 16 channels, 3 kd taps per thread ----
        for (int c4 = 0; c4 < 4; ++c4) {
            float vk[9][4];
#pragma unroll
            for (int kh = 0; kh < 3; ++kh)
#pragma unroll
                for (int kw = 0; kw < 3; ++kw) {
                    float4 t4 = *(const float4*)&vsh[((ty + kh) * 18 + tx + kw) * CP2 + c4 * 4];
                    int k9 = kh * 3 + kw;
                    vk[k9][0] = t4.x; vk[k9][1] = t4.y; vk[k9][2] = t4.z; vk[k9][3] = t4.w;
                }
#pragma unroll
            for (int j = 0; j < 4; ++j) {
                const float* wc = wt + (coff + c4 * 4 + j) * 27;   // wave-uniform -> s_load
#pragma unroll
                for (int k9 = 0; k9 < 9; ++k9) {
                    float vvv = vk[k9][j];
                    acc0 += vvv * wc[k9];
                    acc1 += vvv * wc[9 + k9];
                    acc2 += vvv * wc[18 + k9];
                }
            }
        }
        if (half == 0) __syncthreads();   // protect vsh before next half overwrites
    }

    int gy = tileY * 16 + ty, gx = tileX * 16 + tx;
    size_t pix = (size_t)gy * Ww + gx;
    size_t p0 = ((size_t)(b * 3 + 0) * Dd + d) * HW + pix;
    size_t p1 = ((size_t)(b * 3 + 1) * Dd + d) * HW + pix;
    size_t p2 = ((size_t)(b * 3 + 2) * Dd + d) * HW + pix;
    S[p0] = acc0; S[p1] = acc1; S[p2] = acc2;
}

// ---------------- K3: cost from S, softmax over D, depth + conf -------------
__global__ __launch_bounds__(256)
void k_post(const float* __restrict__ S, const float* __restrict__ dvals,
            float* __restrict__ out) {
    int gid = blockIdx.x * 256 + threadIdx.x;      // 0..B*HW-1
    int b = gid / HW;
    int pix = gid - b * HW;
    const float* S0 = S + ((size_t)(b * 3 + 0) * Dd) * HW + pix;
    const float* S1 = S + ((size_t)(b * 3 + 1) * Dd) * HW + pix;
    const float* S2 = S + ((size_t)(b * 3 + 2) * Dd) * HW + pix;
    float cost[Dd];
#pragma unroll
    for (int d = 0; d < Dd; ++d) {
        float cst = S1[(size_t)d * HW];
        if (d > 0)      cst += S0[(size_t)(d - 1) * HW];
        if (d < Dd - 1) cst += S2[(size_t)(d + 1) * HW];
        cost[d] = cst;
    }
    float m = cost[0];
#pragma unroll
    for (int d = 1; d < Dd; ++d) m = fmaxf(m, cost[d]);
    float sum = 0.f;
#pragma unroll
    for (int d = 0; d < Dd; ++d) { float e = expf(cost[d] - m); cost[d] = e; sum += e; }
    float inv = 1.0f / sum;
    float dep = 0.f, di = 0.f;
#pragma unroll
    for (int d = 0; d < Dd; ++d) {
        float pr = cost[d] * inv;
        dep += pr * dvals[b * Dd + d];
        di += pr * (float)d;
    }
    int didx = (int)di;
    didx = min(max(didx, 0), Dd - 1);
    float conf = 0.f;
#pragma unroll
    for (int d = 0; d < Dd; ++d)
        conf += ((d >= didx - 1) && (d <= didx + 2)) ? cost[d] : 0.f;
    conf *= inv;
    out[gid] = dep;
    out[Bb * HW + gid] = conf;
}

// ---------------- launch ----------------------------------------------------
extern "C" void kernel_launch(void* const* d_in, const int* in_sizes, int n_in,
                              void* d_out, int out_size, void* d_ws, size_t ws_size,
                              hipStream_t stream) {
    const float* features = (const float*)d_in[0];   // (V,B,C,H,W)
    const float* pm       = (const float*)d_in[1];   // (B,V,4,4)
    const float* dvals    = (const float*)d_in[2];   // (B,D)
    const float* reg_w    = (const float*)d_in[4];   // (1,C,3,3,3)
    float* outp = (float*)d_out;

    char* ws = (char*)d_ws;
    float* featT = (float*)ws;                                   // V*B*H*W*C floats
    size_t featT_bytes = (size_t)Vv * Bb * Hh * Ww * Cc * sizeof(float);
    float* P = (float*)(ws + featT_bytes);                       // 48 floats
    float* S = (float*)(ws + featT_bytes + 512);                 // B*3*D*H*W floats

    k_proj<<<1, 64, 0, stream>>>(pm, P);
    k_transpose<<<Vv * Bb * Hh, 256, 0, stream>>>(features, featT);
    k_main<<<dim3(80, Dd, Bb), 256, 0, stream>>>(featT, P, dvals, reg_w, S);
    k_post<<<(Bb * HW) / 256, 256, 0, stream>>>(S, dvals, outp);
}

// Round 3
// 642.476 us; speedup vs baseline: 1.7407x; 1.7407x over previous
//
#include <hip/hip_runtime.h>
#include <hip/hip_bf16.h>

#define Hh 128
#define Ww 160
#define Cc 32
#define Dd 48
#define Bb 2
#define Vv 3
#define HW (Hh*Ww)
#define CP2 20   // padded stride for 16-channel half-tile (16 + 4 pad floats)

// ---------------- K0: proj = src_proj @ inv(ref_proj), extract rot/trans ----
__global__ void k_proj(const float* __restrict__ pm, float* __restrict__ P) {
    int t = threadIdx.x;
    if (t >= Bb * (Vv - 1)) return;
    int b = t >> 1;
    int v = (t & 1) + 1;
    const float* ref = pm + (b * Vv + 0) * 16;
    const float* src = pm + (b * Vv + v) * 16;
    float A[4][8];
    for (int i = 0; i < 4; ++i)
        for (int j = 0; j < 4; ++j) {
            A[i][j] = ref[i * 4 + j];
            A[i][4 + j] = (i == j) ? 1.0f : 0.0f;
        }
    for (int col = 0; col < 4; ++col) {
        int piv = col;
        for (int r = col + 1; r < 4; ++r)
            if (fabsf(A[r][col]) > fabsf(A[piv][col])) piv = r;
        if (piv != col)
            for (int j = 0; j < 8; ++j) { float tmp = A[col][j]; A[col][j] = A[piv][j]; A[piv][j] = tmp; }
        float inv = 1.0f / A[col][col];
        for (int j = 0; j < 8; ++j) A[col][j] *= inv;
        for (int r = 0; r < 4; ++r) {
            if (r == col) continue;
            float f = A[r][col];
            for (int j = 0; j < 8; ++j) A[r][j] -= f * A[col][j];
        }
    }
    float Pm[3][4];
    for (int i = 0; i < 3; ++i)
        for (int j = 0; j < 4; ++j) {
            float s = 0.f;
            for (int k = 0; k < 4; ++k) s += src[i * 4 + k] * A[k][4 + j];
            Pm[i][j] = s;
        }
    float* o = P + t * 12;
    o[0] = Pm[0][0]; o[1] = Pm[0][1]; o[2] = Pm[0][2];
    o[3] = Pm[1][0]; o[4] = Pm[1][1]; o[5] = Pm[1][2];
    o[6] = Pm[2][0]; o[7] = Pm[2][1]; o[8] = Pm[2][2];
    o[9] = Pm[0][3]; o[10] = Pm[1][3]; o[11] = Pm[2][3];
}

// ---------------- K1: transpose (v,b,c,h,w) -> (v,b,h,w,c) ------------------
__global__ void k_transpose(const float* __restrict__ f, float* __restrict__ featT) {
    __shared__ float t[Cc][Ww + 1];
    int slice = blockIdx.x;          // vb*H + y
    int vb = slice / Hh, y = slice % Hh;
    const float* src = f + (size_t)vb * Cc * HW + (size_t)y * Ww;
    float* dst = featT + ((size_t)vb * Hh + y) * Ww * Cc;
    for (int i = threadIdx.x; i < Cc * Ww; i += 256) {
        int c = i / Ww, x = i - c * Ww;
        t[c][x] = src[(size_t)c * HW + x];
    }
    __syncthreads();
    for (int i = threadIdx.x; i < Cc * Ww; i += 256) {
        int x = i >> 5, c = i & 31;
        dst[i] = t[c][x];
    }
}

// ---------------- K2: variance tile + channel-contracted 3x3 conv -> S ------
// Two 16-channel halves through a 26 KB LDS tile.
// launch_bounds(256,4): VGPR cap 128 (NO spills — (256,6) spilled 3.5 GB to
// scratch in R2). Views processed sequentially + int offsets keep natural
// VGPR ~<=84 so HW occupancy reaches 6 blocks/CU via LDS/VGPR limits.
__global__ __launch_bounds__(256, 4)
void k_main(const float* __restrict__ featT, const float* __restrict__ P,
            const float* __restrict__ dvals, const float* __restrict__ wt,
            float* __restrict__ S) {
    __shared__ float vsh[324 * CP2];
    __shared__ float rt[24];
    const int tid = threadIdx.x;
    const int b = blockIdx.z, d = blockIdx.y;
    const int tileY = blockIdx.x / 10, tileX = blockIdx.x - (blockIdx.x / 10) * 10;

    if (tid < 24) rt[tid] = P[b * 24 + tid];
    const float depth = dvals[b * Dd + d];
    const int ty = tid >> 4, tx = tid & 15;
    float acc0 = 0.f, acc1 = 0.f, acc2 = 0.f;
    __syncthreads();

    for (int half = 0; half < 2; ++half) {
        const int coff = half * 16;   // channel offset (floats) into featT pixel
        const float* b1 = featT + (size_t)(1 * Bb + b) * HW * Cc + coff;
        const float* b2 = featT + (size_t)(2 * Bb + b) * HW * Cc + coff;

        // ---- phase 1: fill 18x18 halo variance tile for 16 channels ----
        for (int p = tid; p < 324; p += 256) {
            int pyt = p / 18, pxt = p - pyt * 18;
            int gy = tileY * 16 + pyt - 1, gx = tileX * 16 + pxt - 1;
            float* dst = &vsh[p * CP2];
            if ((unsigned)gy >= (unsigned)Hh || (unsigned)gx >= (unsigned)Ww) {
                float4 z4 = make_float4(0.f, 0.f, 0.f, 0.f);
#pragma unroll
                for (int c4 = 0; c4 < 4; ++c4) *(float4*)&dst[c4 * 4] = z4;
                continue;
            }
            int   off[2][4];
            float wgt[2][4];
#pragma unroll
            for (int vi = 0; vi < 2; ++vi) {
                const float* M = &rt[vi * 12];
                float fgx = (float)gx, fgy = (float)gy;
                float rx = M[0] * fgx + M[1] * fgy + M[2];
                float ry = M[3] * fgx + M[4] * fgy + M[5];
                float rz = M[6] * fgx + M[7] * fgy + M[8];
                float X = rx * depth + M[9];
                float Y = ry * depth + M[10];
                float Z = rz * depth + M[11];
                float z = (fabsf(Z) < 1e-6f) ? 1e-6f : Z;
                float u = X / z, vv = Y / z;
                float x0f = floorf(u), y0f = floorf(vv);
                float fx = u - x0f, fy = vv - y0f;
                int x0 = (int)x0f, y0 = (int)y0f;
                int x1 = x0 + 1, y1 = y0 + 1;
                bool vx0 = (x0 >= 0) && (x0 <= Ww - 1);
                bool vx1 = (x1 >= 0) && (x1 <= Ww - 1);
                bool vy0 = (y0 >= 0) && (y0 <= Hh - 1);
                bool vy1 = (y1 >= 0) && (y1 <= Hh - 1);
                int xc0 = min(max(x0, 0), Ww - 1), xc1 = min(max(x1, 0), Ww - 1);
                int yc0 = min(max(y0, 0), Hh - 1), yc1 = min(max(y1, 0), Hh - 1);
                off[vi][0] = (yc0 * Ww + xc0) * Cc;
                off[vi][1] = (yc0 * Ww + xc1) * Cc;
                off[vi][2] = (yc1 * Ww + xc0) * Cc;
                off[vi][3] = (yc1 * Ww + xc1) * Cc;
                wgt[vi][0] = (vx0 && vy0) ? (1.f - fx) * (1.f - fy) : 0.f;
                wgt[vi][1] = (vx1 && vy0) ? fx * (1.f - fy) : 0.f;
                wgt[vi][2] = (vx0 && vy1) ? (1.f - fx) * fy : 0.f;
                wgt[vi][3] = (vx1 && vy1) ? fx * fy : 0.f;
            }
            const float* pref = featT + ((size_t)b * Hh + gy) * Ww * Cc + (size_t)gx * Cc + coff;
            const float i3 = 1.0f / 3.0f, i9 = 1.0f / 9.0f;
#pragma unroll
            for (int c4 = 0; c4 < 4; ++c4) {
                float4 r = *(const float4*)(pref + c4 * 4);
                float4 sum = r;
                float4 sq;
                sq.x = r.x * r.x; sq.y = r.y * r.y; sq.z = r.z * r.z; sq.w = r.w * r.w;
#pragma unroll
                for (int vi = 0; vi < 2; ++vi) {
                    const float* bs = (vi == 0) ? b1 : b2;
                    float4 c0 = *(const float4*)(bs + off[vi][0] + c4 * 4);
                    float4 c1 = *(const float4*)(bs + off[vi][1] + c4 * 4);
                    float4 c2 = *(const float4*)(bs + off[vi][2] + c4 * 4);
                    float4 c3 = *(const float4*)(bs + off[vi][3] + c4 * 4);
                    float w0 = wgt[vi][0], w1 = wgt[vi][1], w2 = wgt[vi][2], w3 = wgt[vi][3];
                    float4 s;
                    s.x = w0 * c0.x + w1 * c1.x + w2 * c2.x + w3 * c3.x;
                    s.y = w0 * c0.y + w1 * c1.y + w2 * c2.y + w3 * c3.y;
                    s.z = w0 * c0.z + w1 * c1.z + w2 * c2.z + w3 * c3.z;
                    s.w = w0 * c0.w + w1 * c1.w + w2 * c2.w + w3 * c3.w;
                    sum.x += s.x; sum.y += s.y; sum.z += s.z; sum.w += s.w;
                    sq.x += s.x * s.x; sq.y += s.y * s.y; sq.z += s.z * s.z; sq.w += s.w * s.w;
                }
                float4 var;
                var.x = sq.x * i3 - sum.x * sum.x * i9;
                var.y = sq.y * i3 - sum.y * sum.y * i9;
                var.z = sq.z * i3 - sum.z * sum.z * i9;
                var.w = sq.w * i3 - sum.w * sum.w * i9;
                *(float4*)&dst[c4 * 4] = var;
            }
        }
        __syncthreads();

        // ---- phase 2: 3x3 conv over 16 channels, 3 kd taps per thread ----
        for (int c4 = 0; c4 < 4; ++c4) {
            float vk[9][4];
#pragma unroll
            for (int kh = 0; kh < 3; ++kh)
#pragma unroll
                for (int kw = 0; kw < 3; ++kw) {
                    float4 t4 = *(const float4*)&vsh[((ty + kh) * 18 + tx + kw) * CP2 + c4 * 4];
                    int k9 = kh * 3 + kw;
                    vk[k9][0] = t4.x; vk[k9][1] = t4.y; vk[k9][2] = t4.z; vk[k9][3] = t4.w;
                }
#pragma unroll
            for (int j = 0; j < 4; ++j) {
                const float* wc = wt + (coff + c4 * 4 + j) * 27;   // wave-uniform -> s_load
#pragma unroll
                for (int k9 = 0; k9 < 9; ++k9) {
                    float vvv = vk[k9][j];
                    acc0 += vvv * wc[k9];
                    acc1 += vvv * wc[9 + k9];
                    acc2 += vvv * wc[18 + k9];
                }
            }
        }
        if (half == 0) __syncthreads();   // protect vsh before next half overwrites
    }

    int gy = tileY * 16 + ty, gx = tileX * 16 + tx;
    size_t pix = (size_t)gy * Ww + gx;
    size_t p0 = ((size_t)(b * 3 + 0) * Dd + d) * HW + pix;
    size_t p1 = ((size_t)(b * 3 + 1) * Dd + d) * HW + pix;
    size_t p2 = ((size_t)(b * 3 + 2) * Dd + d) * HW + pix;
    S[p0] = acc0; S[p1] = acc1; S[p2] = acc2;
}

// ---------------- K3: cost from S, softmax over D, depth + conf -------------
__global__ __launch_bounds__(256)
void k_post(const float* __restrict__ S, const float* __restrict__ dvals,
            float* __restrict__ out) {
    int gid = blockIdx.x * 256 + threadIdx.x;      // 0..B*HW-1
    int b = gid / HW;
    int pix = gid - b * HW;
    const float* S0 = S + ((size_t)(b * 3 + 0) * Dd) * HW + pix;
    const float* S1 = S + ((size_t)(b * 3 + 1) * Dd) * HW + pix;
    const float* S2 = S + ((size_t)(b * 3 + 2) * Dd) * HW + pix;
    float cost[Dd];
#pragma unroll
    for (int d = 0; d < Dd; ++d) {
        float cst = S1[(size_t)d * HW];
        if (d > 0)      cst += S0[(size_t)(d - 1) * HW];
        if (d < Dd - 1) cst += S2[(size_t)(d + 1) * HW];
        cost[d] = cst;
    }
    float m = cost[0];
#pragma unroll
    for (int d = 1; d < Dd; ++d) m = fmaxf(m, cost[d]);
    float sum = 0.f;
#pragma unroll
    for (int d = 0; d < Dd; ++d) { float e = expf(cost[d] - m); cost[d] = e; sum += e; }
    float inv = 1.0f / sum;
    float dep = 0.f, di = 0.f;
#pragma unroll
    for (int d = 0; d < Dd; ++d) {
        float pr = cost[d] * inv;
        dep += pr * dvals[b * Dd + d];
        di += pr * (float)d;
    }
    int didx = (int)di;
    didx = min(max(didx, 0), Dd - 1);
    float conf = 0.f;
#pragma unroll
    for (int d = 0; d < Dd; ++d)
        conf += ((d >= didx - 1) && (d <= didx + 2)) ? cost[d] : 0.f;
    conf *= inv;
    out[gid] = dep;
    out[Bb * HW + gid] = conf;
}

// ---------------- launch ----------------------------------------------------
extern "C" void kernel_launch(void* const* d_in, const int* in_sizes, int n_in,
                              void* d_out, int out_size, void* d_ws, size_t ws_size,
                              hipStream_t stream) {
    const float* features = (const float*)d_in[0];   // (V,B,C,H,W)
    const float* pm       = (const float*)d_in[1];   // (B,V,4,4)
    const float* dvals    = (const float*)d_in[2];   // (B,D)
    const float* reg_w    = (const float*)d_in[4];   // (1,C,3,3,3)
    float* outp = (float*)d_out;

    char* ws = (char*)d_ws;
    float* featT = (float*)ws;                                   // V*B*H*W*C floats
    size_t featT_bytes = (size_t)Vv * Bb * Hh * Ww * Cc * sizeof(float);
    float* P = (float*)(ws + featT_bytes);                       // 48 floats
    float* S = (float*)(ws + featT_bytes + 512);                 // B*3*D*H*W floats

    k_proj<<<1, 64, 0, stream>>>(pm, P);
    k_transpose<<<Vv * Bb * Hh, 256, 0, stream>>>(features, featT);
    k_main<<<dim3(80, Dd, Bb), 256, 0, stream>>>(featT, P, dvals, reg_w, S);
    k_post<<<(Bb * HW) / 256, 256, 0, stream>>>(S, dvals, outp);
}

// Round 4
// 462.188 us; speedup vs baseline: 2.4198x; 1.3901x over previous
//
#include <hip/hip_runtime.h>
#include <hip/hip_bf16.h>

#define Hh 128
#define Ww 160
#define Cc 32
#define Dd 48
#define Bb 2
#define Vv 3
#define HW (Hh*Ww)
#define CP2 20   // padded stride for 16-channel half-tile (16 + 4 pad floats)

// ---------------- K0: proj = src_proj @ inv(ref_proj), extract rot/trans ----
__global__ void k_proj(const float* __restrict__ pm, float* __restrict__ P) {
    int t = threadIdx.x;
    if (t >= Bb * (Vv - 1)) return;
    int b = t >> 1;
    int v = (t & 1) + 1;
    const float* ref = pm + (b * Vv + 0) * 16;
    const float* src = pm + (b * Vv + v) * 16;
    float A[4][8];
    for (int i = 0; i < 4; ++i)
        for (int j = 0; j < 4; ++j) {
            A[i][j] = ref[i * 4 + j];
            A[i][4 + j] = (i == j) ? 1.0f : 0.0f;
        }
    for (int col = 0; col < 4; ++col) {
        int piv = col;
        for (int r = col + 1; r < 4; ++r)
            if (fabsf(A[r][col]) > fabsf(A[piv][col])) piv = r;
        if (piv != col)
            for (int j = 0; j < 8; ++j) { float tmp = A[col][j]; A[col][j] = A[piv][j]; A[piv][j] = tmp; }
        float inv = 1.0f / A[col][col];
        for (int j = 0; j < 8; ++j) A[col][j] *= inv;
        for (int r = 0; r < 4; ++r) {
            if (r == col) continue;
            float f = A[r][col];
            for (int j = 0; j < 8; ++j) A[r][j] -= f * A[col][j];
        }
    }
    float Pm[3][4];
    for (int i = 0; i < 3; ++i)
        for (int j = 0; j < 4; ++j) {
            float s = 0.f;
            for (int k = 0; k < 4; ++k) s += src[i * 4 + k] * A[k][4 + j];
            Pm[i][j] = s;
        }
    float* o = P + t * 12;
    o[0] = Pm[0][0]; o[1] = Pm[0][1]; o[2] = Pm[0][2];
    o[3] = Pm[1][0]; o[4] = Pm[1][1]; o[5] = Pm[1][2];
    o[6] = Pm[2][0]; o[7] = Pm[2][1]; o[8] = Pm[2][2];
    o[9] = Pm[0][3]; o[10] = Pm[1][3]; o[11] = Pm[2][3];
}

// ---------------- K1: transpose (v,b,c,h,w) -> (v,b,h,w,c) ------------------
__global__ void k_transpose(const float* __restrict__ f, float* __restrict__ featT) {
    __shared__ float t[Cc][Ww + 1];
    int slice = blockIdx.x;          // vb*H + y
    int vb = slice / Hh, y = slice % Hh;
    const float* src = f + (size_t)vb * Cc * HW + (size_t)y * Ww;
    float* dst = featT + ((size_t)vb * Hh + y) * Ww * Cc;
    for (int i = threadIdx.x; i < Cc * Ww; i += 256) {
        int c = i / Ww, x = i - c * Ww;
        t[c][x] = src[(size_t)c * HW + x];
    }
    __syncthreads();
    for (int i = threadIdx.x; i < Cc * Ww; i += 256) {
        int x = i >> 5, c = i & 31;
        dst[i] = t[c][x];
    }
}

// ---------------- K2: variance tile + channel-contracted 3x3 conv -> S ------
// Two 16-channel halves through a 26 KB LDS tile.
// launch_bounds(256,3): ANY bound >=4 on this body makes the allocator spill
// (R2: (256,6) -> 3.5 GB scratch traffic; R3: (256,4) -> 1.1 GB). (256,3)
// gives cap ~170, natural VGPR ~80, zero spill (R1-verified), and actual
// occupancy is then set by LDS 26 KB -> 6 blocks/CU = 24 waves/CU.
__global__ __launch_bounds__(256, 3)
void k_main(const float* __restrict__ featT, const float* __restrict__ P,
            const float* __restrict__ dvals, const float* __restrict__ wt,
            float* __restrict__ S) {
    __shared__ float vsh[324 * CP2];
    __shared__ float rt[24];
    const int tid = threadIdx.x;
    const int b = blockIdx.z, d = blockIdx.y;
    const int tileY = blockIdx.x / 10, tileX = blockIdx.x - (blockIdx.x / 10) * 10;

    if (tid < 24) rt[tid] = P[b * 24 + tid];
    const float depth = dvals[b * Dd + d];
    const int ty = tid >> 4, tx = tid & 15;
    float acc0 = 0.f, acc1 = 0.f, acc2 = 0.f;
    __syncthreads();

    for (int half = 0; half < 2; ++half) {
        const int coff = half * 16;   // channel offset (floats) into featT pixel
        const float* b1 = featT + (size_t)(1 * Bb + b) * HW * Cc + coff;
        const float* b2 = featT + (size_t)(2 * Bb + b) * HW * Cc + coff;

        // ---- phase 1: fill 18x18 halo variance tile for 16 channels ----
        for (int p = tid; p < 324; p += 256) {
            int pyt = p / 18, pxt = p - pyt * 18;
            int gy = tileY * 16 + pyt - 1, gx = tileX * 16 + pxt - 1;
            float* dst = &vsh[p * CP2];
            if ((unsigned)gy >= (unsigned)Hh || (unsigned)gx >= (unsigned)Ww) {
                float4 z4 = make_float4(0.f, 0.f, 0.f, 0.f);
#pragma unroll
                for (int c4 = 0; c4 < 4; ++c4) *(float4*)&dst[c4 * 4] = z4;
                continue;
            }
            int   off[2][4];
            float wgt[2][4];
#pragma unroll
            for (int vi = 0; vi < 2; ++vi) {
                const float* M = &rt[vi * 12];
                float fgx = (float)gx, fgy = (float)gy;
                float rx = M[0] * fgx + M[1] * fgy + M[2];
                float ry = M[3] * fgx + M[4] * fgy + M[5];
                float rz = M[6] * fgx + M[7] * fgy + M[8];
                float X = rx * depth + M[9];
                float Y = ry * depth + M[10];
                float Z = rz * depth + M[11];
                float z = (fabsf(Z) < 1e-6f) ? 1e-6f : Z;
                float u = X / z, vv = Y / z;
                float x0f = floorf(u), y0f = floorf(vv);
                float fx = u - x0f, fy = vv - y0f;
                int x0 = (int)x0f, y0 = (int)y0f;
                int x1 = x0 + 1, y1 = y0 + 1;
                bool vx0 = (x0 >= 0) && (x0 <= Ww - 1);
                bool vx1 = (x1 >= 0) && (x1 <= Ww - 1);
                bool vy0 = (y0 >= 0) && (y0 <= Hh - 1);
                bool vy1 = (y1 >= 0) && (y1 <= Hh - 1);
                int xc0 = min(max(x0, 0), Ww - 1), xc1 = min(max(x1, 0), Ww - 1);
                int yc0 = min(max(y0, 0), Hh - 1), yc1 = min(max(y1, 0), Hh - 1);
                off[vi][0] = (yc0 * Ww + xc0) * Cc;
                off[vi][1] = (yc0 * Ww + xc1) * Cc;
                off[vi][2] = (yc1 * Ww + xc0) * Cc;
                off[vi][3] = (yc1 * Ww + xc1) * Cc;
                wgt[vi][0] = (vx0 && vy0) ? (1.f - fx) * (1.f - fy) : 0.f;
                wgt[vi][1] = (vx1 && vy0) ? fx * (1.f - fy) : 0.f;
                wgt[vi][2] = (vx0 && vy1) ? (1.f - fx) * fy : 0.f;
                wgt[vi][3] = (vx1 && vy1) ? fx * fy : 0.f;
            }
            const float* pref = featT + ((size_t)b * Hh + gy) * Ww * Cc + (size_t)gx * Cc + coff;
            const float i3 = 1.0f / 3.0f, i9 = 1.0f / 9.0f;
#pragma unroll
            for (int c4 = 0; c4 < 4; ++c4) {
                float4 r = *(const float4*)(pref + c4 * 4);
                float4 sum = r;
                float4 sq;
                sq.x = r.x * r.x; sq.y = r.y * r.y; sq.z = r.z * r.z; sq.w = r.w * r.w;
#pragma unroll
                for (int vi = 0; vi < 2; ++vi) {
                    const float* bs = (vi == 0) ? b1 : b2;
                    float4 c0 = *(const float4*)(bs + off[vi][0] + c4 * 4);
                    float4 c1 = *(const float4*)(bs + off[vi][1] + c4 * 4);
                    float4 c2 = *(const float4*)(bs + off[vi][2] + c4 * 4);
                    float4 c3 = *(const float4*)(bs + off[vi][3] + c4 * 4);
                    float w0 = wgt[vi][0], w1 = wgt[vi][1], w2 = wgt[vi][2], w3 = wgt[vi][3];
                    float4 s;
                    s.x = w0 * c0.x + w1 * c1.x + w2 * c2.x + w3 * c3.x;
                    s.y = w0 * c0.y + w1 * c1.y + w2 * c2.y + w3 * c3.y;
                    s.z = w0 * c0.z + w1 * c1.z + w2 * c2.z + w3 * c3.z;
                    s.w = w0 * c0.w + w1 * c1.w + w2 * c2.w + w3 * c3.w;
                    sum.x += s.x; sum.y += s.y; sum.z += s.z; sum.w += s.w;
                    sq.x += s.x * s.x; sq.y += s.y * s.y; sq.z += s.z * s.z; sq.w += s.w * s.w;
                }
                float4 var;
                var.x = sq.x * i3 - sum.x * sum.x * i9;
                var.y = sq.y * i3 - sum.y * sum.y * i9;
                var.z = sq.z * i3 - sum.z * sum.z * i9;
                var.w = sq.w * i3 - sum.w * sum.w * i9;
                *(float4*)&dst[c4 * 4] = var;
            }
        }
        __syncthreads();

        // ---- phase 2: 3x3 conv over 16 channels, 3 kd taps per thread ----
        for (int c4 = 0; c4 < 4; ++c4) {
            float vk[9][4];
#pragma unroll
            for (int kh = 0; kh < 3; ++kh)
#pragma unroll
                for (int kw = 0; kw < 3; ++kw) {
                    float4 t4 = *(const float4*)&vsh[((ty + kh) * 18 + tx + kw) * CP2 + c4 * 4];
                    int k9 = kh * 3 + kw;
                    vk[k9][0] = t4.x; vk[k9][1] = t4.y; vk[k9][2] = t4.z; vk[k9][3] = t4.w;
                }
#pragma unroll
            for (int j = 0; j < 4; ++j) {
                const float* wc = wt + (coff + c4 * 4 + j) * 27;   // wave-uniform -> s_load
#pragma unroll
                for (int k9 = 0; k9 < 9; ++k9) {
                    float vvv = vk[k9][j];
                    acc0 += vvv * wc[k9];
                    acc1 += vvv * wc[9 + k9];
                    acc2 += vvv * wc[18 + k9];
                }
            }
        }
        if (half == 0) __syncthreads();   // protect vsh before next half overwrites
    }

    int gy = tileY * 16 + ty, gx = tileX * 16 + tx;
    size_t pix = (size_t)gy * Ww + gx;
    size_t p0 = ((size_t)(b * 3 + 0) * Dd + d) * HW + pix;
    size_t p1 = ((size_t)(b * 3 + 1) * Dd + d) * HW + pix;
    size_t p2 = ((size_t)(b * 3 + 2) * Dd + d) * HW + pix;
    S[p0] = acc0; S[p1] = acc1; S[p2] = acc2;
}

// ---------------- K3: cost from S, softmax over D, depth + conf -------------
__global__ __launch_bounds__(256)
void k_post(const float* __restrict__ S, const float* __restrict__ dvals,
            float* __restrict__ out) {
    int gid = blockIdx.x * 256 + threadIdx.x;      // 0..B*HW-1
    int b = gid / HW;
    int pix = gid - b * HW;
    const float* S0 = S + ((size_t)(b * 3 + 0) * Dd) * HW + pix;
    const float* S1 = S + ((size_t)(b * 3 + 1) * Dd) * HW + pix;
    const float* S2 = S + ((size_t)(b * 3 + 2) * Dd) * HW + pix;
    float cost[Dd];
#pragma unroll
    for (int d = 0; d < Dd; ++d) {
        float cst = S1[(size_t)d * HW];
        if (d > 0)      cst += S0[(size_t)(d - 1) * HW];
        if (d < Dd - 1) cst += S2[(size_t)(d + 1) * HW];
        cost[d] = cst;
    }
    float m = cost[0];
#pragma unroll
    for (int d = 1; d < Dd; ++d) m = fmaxf(m, cost[d]);
    float sum = 0.f;
#pragma unroll
    for (int d = 0; d < Dd; ++d) { float e = expf(cost[d] - m); cost[d] = e; sum += e; }
    float inv = 1.0f / sum;
    float dep = 0.f, di = 0.f;
#pragma unroll
    for (int d = 0; d < Dd; ++d) {
        float pr = cost[d] * inv;
        dep += pr * dvals[b * Dd + d];
        di += pr * (float)d;
    }
    int didx = (int)di;
    didx = min(max(didx, 0), Dd - 1);
    float conf = 0.f;
#pragma unroll
    for (int d = 0; d < Dd; ++d)
        conf += ((d >= didx - 1) && (d <= didx + 2)) ? cost[d] : 0.f;
    conf *= inv;
    out[gid] = dep;
    out[Bb * HW + gid] = conf;
}

// ---------------- launch ----------------------------------------------------
extern "C" void kernel_launch(void* const* d_in, const int* in_sizes, int n_in,
                              void* d_out, int out_size, void* d_ws, size_t ws_size,
                              hipStream_t stream) {
    const float* features = (const float*)d_in[0];   // (V,B,C,H,W)
    const float* pm       = (const float*)d_in[1];   // (B,V,4,4)
    const float* dvals    = (const float*)d_in[2];   // (B,D)
    const float* reg_w    = (const float*)d_in[4];   // (1,C,3,3,3)
    float* outp = (float*)d_out;

    char* ws = (char*)d_ws;
    float* featT = (float*)ws;                                   // V*B*H*W*C floats
    size_t featT_bytes = (size_t)Vv * Bb * Hh * Ww * Cc * sizeof(float);
    float* P = (float*)(ws + featT_bytes);                       // 48 floats
    float* S = (float*)(ws + featT_bytes + 512);                 // B*3*D*H*W floats

    k_proj<<<1, 64, 0, stream>>>(pm, P);
    k_transpose<<<Vv * Bb * Hh, 256, 0, stream>>>(features, featT);
    k_main<<<dim3(80, Dd, Bb), 256, 0, stream>>>(featT, P, dvals, reg_w, S);
    k_post<<<(Bb * HW) / 256, 256, 0, stream>>>(S, dvals, outp);
}